// Round 5
// baseline (1278.986 us; speedup 1.0000x reference)
//
#include <hip/hip_runtime.h>
#include <math.h>

#define N_NODES 10000
#define N_EDGES 160000
#define EPS 1e-8f

typedef __attribute__((ext_vector_type(8))) __bf16 bf16x8;
typedef __attribute__((ext_vector_type(4))) float f32x4;

__device__ __forceinline__ f32x4 MFMA(bf16x8 a, bf16x8 b, f32x4 c){
  return __builtin_amdgcn_mfma_f32_16x16x32_bf16(a, b, c, 0, 0, 0);
}

__device__ __forceinline__ float wave_sum64(float x) {
  #pragma unroll
  for (int m = 32; m >= 1; m >>= 1) x += __shfl_xor(x, m, 64);
  return x;
}
__device__ __forceinline__ float gsum16(float x) {
  x += __shfl_xor(x, 1, 64); x += __shfl_xor(x, 2, 64);
  x += __shfl_xor(x, 4, 64); x += __shfl_xor(x, 8, 64);
  return x;
}

// ---- LDS (bf16 element offsets), 32-edge tile, XOR-swizzled X tiles ----
// X0: [0, 6144)       32 rows x 192   byte ^= (row&7)<<4
// X1: [6144, 15360)   96 rows x 96    (row = m*32+eg)
// X2: [15360, 25600)  160 rows x 64   (c16|e16|n16|zero16)
// aliases (unswizzled, own lifetime):
// O0: [0, 3840)       32 x 120
// O1: [6144, 9984)    96 x 40
// O2: [15360, 21760)  160 x 40
// Wv: [21760, 25600)  32 x 120   (dead X2 tail; written after bar3)
#define X0O 0
#define X1O 6144
#define X2O 15360
#define O0O 0
#define O1O 6144
#define O2O 15360
#define WvO 21760
#define SMEM_BYTES 52352   // 51200 bf16 + 1024 gates + 128 ecs

// swizzled-weight offsets (bf16 elements) -- validated layout
#define W0O 0
#define W1O 196608
#define W2O 221184
#define WEO 229376
#define P0O 245760
#define P1O 249856
#define P2O 250880
#define WTOT 251392

// ---------------- weight pre-swizzle ----------------
__device__ __forceinline__ void prep_seg(int u, const float* __restrict__ src,
                                         __bf16* __restrict__ dst,
                                         int NT, int KS, int Ka, int Na) {
  int per = NT * KS * 512;
  int e = u / per; int r = u - e * per;
  int nt = r / (KS * 512); r -= nt * KS * 512;
  int ks = r >> 9; int li = r & 511;
  int lane = li >> 3, j = li & 7;
  int k = ks * 32 + ((lane >> 4) << 3) + j;
  int n = nt * 16 + (lane & 15);
  float v = (k < Ka && n < Na) ? src[((size_t)e * Ka + k) * Na + n] : 0.f;
  dst[u] = (__bf16)v;
}

__global__ __launch_bounds__(256)
void k_prep(const float* __restrict__ W0, const float* __restrict__ W1,
            const float* __restrict__ W2, const float* __restrict__ We,
            const float* __restrict__ P0, const float* __restrict__ P1,
            const float* __restrict__ P2, __bf16* __restrict__ dst) {
  int t = blockIdx.x * 256 + threadIdx.x;
  if (t >= WTOT) return;
  if      (t < W1O) prep_seg(t - W0O, W0, dst + W0O, 8, 6, 192, 112);
  else if (t < W2O) prep_seg(t - W1O, W1, dst + W1O, 2, 3,  96,  32);
  else if (t < WEO) prep_seg(t - W2O, W2, dst + W2O, 1, 2,  48,  16);
  else if (t < P0O) prep_seg(t - WEO, We, dst + WEO, 8, 4, 128, 112);
  else if (t < P1O) prep_seg(t - P0O, P0, dst + P0O, 4, 2,  64,  64);
  else if (t < P2O) prep_seg(t - P1O, P1, dst + P1O, 2, 1,  32,  32);
  else              prep_seg(t - P2O, P2, dst + P2O, 1, 1,  16,  16);
}

// ---------------- node separable LN -> bf16, fragment-reordered ----------------
__global__ __launch_bounds__(256)
void k_node_ln(const float* __restrict__ nf, const float* __restrict__ gn,
               const float* __restrict__ bn, __bf16* __restrict__ nfn) {
  int node = blockIdx.x * 4 + (threadIdx.x >> 6);
  int lane = threadIdx.x & 63;
  const float* row = nf + (size_t)node * 240;
  __bf16* out = nfn + (size_t)node * 240;
  float s = row[lane];
  float mean = wave_sum64(s) * (1.f / 64.f);
  float d = s - mean;
  float var = wave_sum64(d * d) * (1.f / 64.f);
  float rstd = rsqrtf(var + EPS);
  out[lane] = (__bf16)(d * rstd * gn[lane] + bn[lane]);
  float v0 = row[64 + lane];
  float v1 = (lane < 32) ? row[128 + lane] : 0.f;
  float rsv = rsqrtf(wave_sum64(v0 * v0 + v1 * v1) * (1.f / 96.f) + EPS);
  { int vi = lane; int i = vi / 3, m = vi - 3 * i;
    out[64 + m * 32 + i] = (__bf16)(v0 * rsv * gn[64 + i]); }
  if (lane < 32) { int vi = 64 + lane; int i = vi / 3, m = vi - 3 * i;
    out[64 + m * 32 + i] = (__bf16)(v1 * rsv * gn[64 + i]); }
  float t0 = row[160 + lane];
  float t1 = (lane < 16) ? row[224 + lane] : 0.f;
  float rst = rsqrtf(wave_sum64(t0 * t0 + t1 * t1) * (1.f / 80.f) + EPS);
  { int ti = lane; int i = ti / 5, m = ti - 5 * i;
    out[160 + m * 16 + i] = (__bf16)(t0 * rst * gn[96 + i]); }
  if (lane < 16) { int ti = 64 + lane; int i = ti / 5, m = ti - 5 * i;
    out[160 + m * 16 + i] = (__bf16)(t1 * rst * gn[96 + i]); }
}

// ---------------- edge LN stats ----------------
__global__ __launch_bounds__(256)
void k_stats(const float* __restrict__ ef, float4* __restrict__ stats) {
  int row = blockIdx.x * 4 + (threadIdx.x >> 6);
  int lane = threadIdx.x & 63;
  const float* r = ef + (size_t)row * 240;
  float s = r[lane];
  float mean = wave_sum64(s) * (1.f / 64.f);
  float d = s - mean;
  float var = wave_sum64(d * d) * (1.f / 64.f);
  float rstd = rsqrtf(var + EPS);
  float v0 = r[64 + lane];
  float v1 = (lane < 32) ? r[128 + lane] : 0.f;
  float rsv = rsqrtf(wave_sum64(v0 * v0 + v1 * v1) * (1.f / 96.f) + EPS);
  float t0 = r[160 + lane];
  float t1 = (lane < 16) ? r[224 + lane] : 0.f;
  float rst = rsqrtf(wave_sum64(t0 * t0 + t1 * t1) * (1.f / 80.f) + EPS);
  if (lane == 0) stats[row] = make_float4(mean, rstd, rsv, rst);
}

// ---------------- gates: softmax(latents @ Wg) ----------------
__global__ __launch_bounds__(256)
void k_gate(const float* __restrict__ latents, const float* __restrict__ Wg,
            float* __restrict__ gatesG) {
  int row = blockIdx.x * 16 + (threadIdx.x >> 4);
  int sl = threadIdx.x & 15;
  const float* lrow = latents + (size_t)row * 128 + sl * 8;
  float4 u4 = *(const float4*)lrow;
  float4 w4 = *(const float4*)(lrow + 4);
  float lv[8] = {u4.x, u4.y, u4.z, u4.w, w4.x, w4.y, w4.z, w4.w};
  float ga[8] = {};
  #pragma unroll
  for (int dd = 0; dd < 8; ++dd) {
    const float* wgr = Wg + (sl * 8 + dd) * 8;
    #pragma unroll
    for (int k = 0; k < 8; ++k) ga[k] += lv[dd] * wgr[k];
  }
  #pragma unroll
  for (int k = 0; k < 8; ++k) ga[k] = gsum16(ga[k]);
  float mx = ga[0];
  #pragma unroll
  for (int k = 1; k < 8; ++k) mx = fmaxf(mx, ga[k]);
  float den = 0.f;
  #pragma unroll
  for (int k = 0; k < 8; ++k) { ga[k] = expf(ga[k] - mx); den += ga[k]; }
  float val = 0.f;
  #pragma unroll
  for (int k = 0; k < 8; ++k) if (sl == k) val = ga[k];
  if (sl < 8) gatesG[(size_t)row * 8 + sl] = val / den;
}

// ---------------- fused edge kernel (MFMA), 32 edges/block, 3 blocks/CU ----------------
__global__ __launch_bounds__(512, 6)
void k_edge(const float* __restrict__ latents, const float* __restrict__ ef,
            const __bf16* __restrict__ nfn, const int* __restrict__ eidx,
            const float* __restrict__ ln_ge, const float* __restrict__ ln_be,
            const float4* __restrict__ stats, const float* __restrict__ gatesG,
            const __bf16* __restrict__ Wsw,
            const float* __restrict__ pb0, const float* __restrict__ benv,
            float* __restrict__ agg) {
  __shared__ __align__(16) char smem[SMEM_BYTES];
  float* gatesL = (float*)(smem + 51200);
  int* ecsL = (int*)(smem + 52224);
  __bf16* SBF = (__bf16*)smem;

  const int tid = threadIdx.x;
  const int e0 = blockIdx.x * 32;
  const int w = tid >> 6, lane = tid & 63, kg = lane >> 4, l16 = lane & 15;
  const int eg = tid >> 4, sl = tid & 15;
  const int xsw = (eg & 7) << 4;          // staging-side swizzle (row&7 == eg&7)
  const int xswr = (l16 & 7) << 4;        // MFMA-A-read swizzle (row&7 == l16&7)

  // ---- hoisted loads ----
  const int ec = eidx[e0 + eg], en = eidx[N_EDGES + e0 + eg];
  if (tid < 32) ecsL[tid] = eidx[e0 + tid];
  if (tid < 256) gatesL[tid] = gatesG[(size_t)e0 * 8 + tid];
  uint2 cvr[4], nvr[4]; float4 evf[4];
  #pragma unroll
  for (int j = 0; j < 4; ++j) {
    int ch = j * 16 + sl;
    if (ch < 60) {
      int p = ch * 4;
      cvr[j] = *(const uint2*)(nfn + (size_t)ec * 240 + p);
      nvr[j] = *(const uint2*)(nfn + (size_t)en * 240 + p);
      evf[j] = *(const float4*)(ef + (size_t)(e0 + eg) * 240 + p);
    }
  }
  float4 st = stats[e0 + eg];   // mean, rstd, rsv, rst

  // ================= staging (pure copies + affine; no shuffles) =================
  {
    #pragma unroll
    for (int j = 0; j < 4; ++j) {
      int ch = j * 16 + sl;
      if (ch < 60) {
        int p = ch * 4;
        float e4[4] = {evf[j].x, evf[j].y, evf[j].z, evf[j].w};
        if (p < 64) {
          int off = X0O + eg * 192;
          *(uint2*)(smem + (((off + p) * 2) ^ xsw)) = cvr[j];
          *(uint2*)(smem + (((off + 128 + p) * 2) ^ xsw)) = nvr[j];
          __bf16 eb[4];
          #pragma unroll
          for (int t = 0; t < 4; ++t) {
            int c = p + t;
            eb[t] = (__bf16)((e4[t] - st.x) * st.y * ln_ge[c] + ln_be[c]);
          }
          *(uint2*)(smem + (((off + 64 + p) * 2) ^ xsw)) = *(uint2*)eb;
        } else if (p < 160) {
          int q = p - 64;
          int m = q >> 5, i = q & 31;
          int off = X1O + (m * 32 + eg) * 96;
          *(uint2*)(smem + (((off + i) * 2) ^ xsw)) = cvr[j];
          *(uint2*)(smem + (((off + 64 + i) * 2) ^ xsw)) = nvr[j];
          #pragma unroll
          for (int t = 0; t < 4; ++t) {
            int k = q + t; int ei = k / 3, em = k - 3 * ei;
            float y = e4[t] * st.z * ln_ge[64 + ei];
            *(__bf16*)(smem + (((X1O + (em * 32 + eg) * 96 + 32 + ei) * 2) ^ xsw)) = (__bf16)y;
          }
        } else {
          int q = p - 160;
          int m = q >> 4, i = q & 15;
          int off = X2O + (m * 32 + eg) * 64;
          *(uint2*)(smem + (((off + i) * 2) ^ xsw)) = cvr[j];
          *(uint2*)(smem + (((off + 32 + i) * 2) ^ xsw)) = nvr[j];
          #pragma unroll
          for (int t = 0; t < 4; ++t) {
            int k = q + t; int ei = k / 5, em = k - 5 * ei;
            float y = e4[t] * st.w * ln_ge[96 + ei];
            *(__bf16*)(smem + (((X2O + (em * 32 + eg) * 64 + 16 + ei) * 2) ^ xsw)) = (__bf16)y;
          }
        }
      }
    }
    // X2 K-pad zeros (cols 48..63), swizzled
    for (int z = tid; z < 640; z += 512) {
      int r = z >> 2, c4 = (z & 3) * 4;
      uint2 zz; zz.x = 0; zz.y = 0;
      *(uint2*)(smem + (((X2O + r * 64 + 48 + c4) * 2) ^ ((r & 7) << 4))) = zz;
    }
  }
  __syncthreads();   // bar0: X0/X1/X2/gates/ecs ready

  // ================= l0 MoE + fused silu/sigmoid epilogue =================
  {
    const int mt = w & 1, ntA = (w >> 1) * 2;
    f32x4 acc[2] = {};
    const __bf16* WB = Wsw + W0O;
    for (int ex = 0; ex < 8; ++ex) {
      f32x4 D[2] = {};
      #pragma unroll
      for (int ks = 0; ks < 6; ++ks) {
        bf16x8 a = *(const bf16x8*)(smem + (((X0O + (mt * 16 + l16) * 192 + ks * 32 + kg * 8) * 2) ^ xswr));
        bf16x8 bA = *(const bf16x8*)(WB + (((ex * 8 + ntA) * 6 + ks) << 9) + lane * 8);
        bf16x8 bB = *(const bf16x8*)(WB + (((ex * 8 + ntA + 1) * 6 + ks) << 9) + lane * 8);
        D[0] = MFMA(a, bA, D[0]); D[1] = MFMA(a, bB, D[1]);
      }
      #pragma unroll
      for (int jj = 0; jj < 4; ++jj) {
        float g = gatesL[(mt * 16 + kg * 4 + jj) * 8 + ex];
        acc[0][jj] += g * D[0][jj]; acc[1][jj] += g * D[1][jj];
      }
    }
    __syncthreads();   // bar1: all waves done reading X0
    #pragma unroll
    for (int ni = 0; ni < 2; ++ni) {
      int cc = (ntA + ni) * 16 + l16;
      if (cc < 112)
        #pragma unroll
        for (int jj = 0; jj < 4; ++jj) {
          float x = acc[ni][jj];
          float sg = 1.f / (1.f + expf(-x));
          float val = (cc < 64) ? x * sg : sg;
          SBF[O0O + (mt * 16 + kg * 4 + jj) * 120 + cc] = (__bf16)val;
        }
    }
  }

  // ================= l1 MoE + gated epilogue =================
  const int nu1 = (w < 4) ? 2 : 1;
  const int mtv0 = w >> 1, ntv = w & 1, mtv1 = (w >> 1) + 4;
  {
    f32x4 acc[2] = {};
    const __bf16* WB = Wsw + W1O;
    for (int ex = 0; ex < 8; ++ex) {
      f32x4 D[2] = {};
      #pragma unroll
      for (int ks = 0; ks < 3; ++ks) {
        bf16x8 b = *(const bf16x8*)(WB + (((ex * 2 + ntv) * 3 + ks) << 9) + lane * 8);
        bf16x8 a0 = *(const bf16x8*)(smem + (((X1O + (mtv0 * 16 + l16) * 96 + ks * 32 + kg * 8) * 2) ^ xswr));
        D[0] = MFMA(a0, b, D[0]);
        if (nu1 == 2) {
          bf16x8 a1 = *(const bf16x8*)(smem + (((X1O + (mtv1 * 16 + l16) * 96 + ks * 32 + kg * 8) * 2) ^ xswr));
          D[1] = MFMA(a1, b, D[1]);
        }
      }
      #pragma unroll
      for (int jj = 0; jj < 4; ++jj) {
        int r0 = mtv0 * 16 + kg * 4 + jj;
        acc[0][jj] += gatesL[(r0 & 31) * 8 + ex] * D[0][jj];
        if (nu1 == 2) {
          int r1 = mtv1 * 16 + kg * 4 + jj;
          acc[1][jj] += gatesL[(r1 & 31) * 8 + ex] * D[1][jj];
        }
      }
    }
    __syncthreads();   // bar2: X1 reads done; O0 visible
    const int o = ntv * 16 + l16;
    #pragma unroll
    for (int jj = 0; jj < 4; ++jj) {
      int r0 = mtv0 * 16 + kg * 4 + jj;
      float g0 = (float)SBF[O0O + (r0 & 31) * 120 + 64 + o];
      SBF[O1O + r0 * 40 + o] = (__bf16)(acc[0][jj] * g0);
      if (nu1 == 2) {
        int r1 = mtv1 * 16 + kg * 4 + jj;
        float g1 = (float)SBF[O0O + (r1 & 31) * 120 + 64 + o];
        SBF[O1O + r1 * 40 + o] = (__bf16)(acc[1][jj] * g1);
      }
    }
  }

  // ================= l2 MoE + gated epilogue =================
  const int nu2 = (w < 2) ? 2 : 1;
  const int mt20 = w, mt21 = w + 8;
  {
    f32x4 acc[2] = {};
    const __bf16* WB = Wsw + W2O;
    for (int ex = 0; ex < 8; ++ex) {
      f32x4 D[2] = {};
      #pragma unroll
      for (int ks = 0; ks < 2; ++ks) {
        bf16x8 b = *(const bf16x8*)(WB + ((ex * 2 + ks) << 9) + lane * 8);
        bf16x8 a0 = *(const bf16x8*)(smem + (((X2O + (mt20 * 16 + l16) * 64 + ks * 32 + kg * 8) * 2) ^ xswr));
        D[0] = MFMA(a0, b, D[0]);
        if (nu2 == 2) {
          bf16x8 a1 = *(const bf16x8*)(smem + (((X2O + (mt21 * 16 + l16) * 64 + ks * 32 + kg * 8) * 2) ^ xswr));
          D[1] = MFMA(a1, b, D[1]);
        }
      }
      #pragma unroll
      for (int jj = 0; jj < 4; ++jj) {
        int r0 = mt20 * 16 + kg * 4 + jj;
        acc[0][jj] += gatesL[(r0 & 31) * 8 + ex] * D[0][jj];
        if (nu2 == 2) {
          int r1 = mt21 * 16 + kg * 4 + jj;
          acc[1][jj] += gatesL[(r1 & 31) * 8 + ex] * D[1][jj];
        }
      }
    }
    __syncthreads();   // bar3: X2 reads done
    #pragma unroll
    for (int jj = 0; jj < 4; ++jj) {
      int r0 = mt20 * 16 + kg * 4 + jj;
      float g0 = (float)SBF[O0O + (r0 & 31) * 120 + 96 + l16];
      SBF[O2O + r0 * 40 + l16] = (__bf16)(acc[0][jj] * g0);
      SBF[O2O + r0 * 40 + 16 + l16] = (__bf16)0.f;
      if (nu2 == 2) {
        int r1 = mt21 * 16 + kg * 4 + jj;
        float g1 = (float)SBF[O0O + (r1 & 31) * 120 + 96 + l16];
        SBF[O2O + r1 * 40 + l16] = (__bf16)(acc[1][jj] * g1);
        SBF[O2O + r1 * 40 + 16 + l16] = (__bf16)0.f;
      }
    }
  }

  // ================= env weights (latents @ Wenv + benv) -> Wv (X2 tail) =====
  {
    const int mt = w >> 2, np = (w & 3) * 2;
    f32x4 acc[2] = {};
    const __bf16* WB = Wsw + WEO;
    #pragma unroll
    for (int ks = 0; ks < 4; ++ks) {
      bf16x8 a;
      const float* lp = latents + (size_t)(e0 + mt * 16 + l16) * 128 + ks * 32 + kg * 8;
      float4 u4 = *(const float4*)lp; float4 v4 = *(const float4*)(lp + 4);
      a[0]=(__bf16)u4.x; a[1]=(__bf16)u4.y; a[2]=(__bf16)u4.z; a[3]=(__bf16)u4.w;
      a[4]=(__bf16)v4.x; a[5]=(__bf16)v4.y; a[6]=(__bf16)v4.z; a[7]=(__bf16)v4.w;
      bf16x8 bA = *(const bf16x8*)(WB + ((np * 4 + ks) << 9) + lane * 8);
      bf16x8 bB = *(const bf16x8*)(WB + (((np + 1) * 4 + ks) << 9) + lane * 8);
      acc[0] = MFMA(a, bA, acc[0]); acc[1] = MFMA(a, bB, acc[1]);
    }
    #pragma unroll
    for (int ni = 0; ni < 2; ++ni) {
      int cc = (np + ni) * 16 + l16;
      if (cc < 112) {
        float bv = benv[cc];
        #pragma unroll
        for (int jj = 0; jj < 4; ++jj)
          SBF[WvO + (mt * 16 + kg * 4 + jj) * 120 + cc] = (__bf16)(acc[ni][jj] + bv);
      }
    }
  }
  __syncthreads();   // bar4: O0/O1/O2/Wv all visible

  // ================= lin_post s-path + coalesced scatter =================
  {
    const int mt = w & 1, nt = w >> 1;
    f32x4 ps = {};
    const __bf16* WB = Wsw + P0O;
    #pragma unroll
    for (int ks = 0; ks < 2; ++ks) {
      bf16x8 a = *(const bf16x8*)(SBF + O0O + (mt * 16 + l16) * 120 + ks * 32 + kg * 8);
      bf16x8 b = *(const bf16x8*)(WB + ((nt * 2 + ks) << 9) + lane * 8);
      ps = MFMA(a, b, ps);
    }
    int cc = nt * 16 + l16;
    float bias = pb0[cc];
    #pragma unroll
    for (int jj = 0; jj < 4; ++jj) {
      int row = mt * 16 + kg * 4 + jj;
      float msg = (ps[jj] + bias) * (float)SBF[WvO + row * 120 + cc];
      atomicAdd(&agg[(size_t)ecsL[row] * 240 + cc], msg);
    }
  }
  // ================= lin_post v-path + coalesced scatter =================
  {
    f32x4 pv[2] = {};
    const __bf16* WB = Wsw + P1O;
    bf16x8 b = *(const bf16x8*)(WB + (ntv << 9) + lane * 8);
    bf16x8 a0 = *(const bf16x8*)(SBF + O1O + (mtv0 * 16 + l16) * 40 + kg * 8);
    pv[0] = MFMA(a0, b, pv[0]);
    if (nu1 == 2) {
      bf16x8 a1 = *(const bf16x8*)(SBF + O1O + (mtv1 * 16 + l16) * 40 + kg * 8);
      pv[1] = MFMA(a1, b, pv[1]);
    }
    const int o = ntv * 16 + l16;
    #pragma unroll
    for (int jj = 0; jj < 4; ++jj) {
      int r0 = mtv0 * 16 + kg * 4 + jj;
      int m = r0 >> 5, eL = r0 & 31;
      float msg = pv[0][jj] * (float)SBF[WvO + eL * 120 + 64 + o];
      atomicAdd(&agg[(size_t)ecsL[eL] * 240 + 64 + m * 32 + o], msg);
      if (nu1 == 2) {
        int r1 = mtv1 * 16 + kg * 4 + jj;
        int m1 = r1 >> 5, eL1 = r1 & 31;
        float msg1 = pv[1][jj] * (float)SBF[WvO + eL1 * 120 + 64 + o];
        atomicAdd(&agg[(size_t)ecsL[eL1] * 240 + 64 + m1 * 32 + o], msg1);
      }
    }
  }
  // ================= lin_post t-path + coalesced scatter =================
  {
    f32x4 pt[2] = {};
    const __bf16* WB = Wsw + P2O;
    bf16x8 b = *(const bf16x8*)(WB + lane * 8);
    bf16x8 a0 = *(const bf16x8*)(SBF + O2O + (mt20 * 16 + l16) * 40 + kg * 8);
    pt[0] = MFMA(a0, b, pt[0]);
    if (nu2 == 2) {
      bf16x8 a1 = *(const bf16x8*)(SBF + O2O + (mt21 * 16 + l16) * 40 + kg * 8);
      pt[1] = MFMA(a1, b, pt[1]);
    }
    const int o = l16;
    #pragma unroll
    for (int jj = 0; jj < 4; ++jj) {
      int r0 = mt20 * 16 + kg * 4 + jj;
      int m = r0 >> 5, eL = r0 & 31;
      float msg = pt[0][jj] * (float)SBF[WvO + eL * 120 + 96 + o];
      atomicAdd(&agg[(size_t)ecsL[eL] * 240 + 160 + m * 16 + o], msg);
      if (nu2 == 2) {
        int r1 = mt21 * 16 + kg * 4 + jj;
        int m1 = r1 >> 5, eL1 = r1 & 31;
        float msg1 = pt[1][jj] * (float)SBF[WvO + eL1 * 120 + 96 + o];
        atomicAdd(&agg[(size_t)ecsL[eL1] * 240 + 160 + m1 * 16 + o], msg1);
      }
    }
  }
}

// ---------------- node residual + species TP (agg in reordered layout) ----------------
__global__ __launch_bounds__(256)
void k_node(const float* __restrict__ nf, const float* __restrict__ agg,
            const float* __restrict__ onehot, const float* __restrict__ T0,
            const float* __restrict__ T1, const float* __restrict__ T2,
            float* __restrict__ out) {
  int w = threadIdx.x >> 6;
  int lane = threadIdx.x & 63;
  int node = blockIdx.x * 4 + w;
  __shared__ float buf[4][240];
  const float* nrow = nf + (size_t)node * 240;
  const float* arow = agg + (size_t)node * 240;
  const float c_old = 0.894427190999916f;
  const float c_new_s = 0.447213595499958f * 0.25f;
  for (int j = lane; j < 240; j += 64) {
    int src;
    if (j < 64) src = j;
    else if (j < 160) { int vi = j - 64; int o = vi / 3, m = vi - 3 * o; src = 64 + m * 32 + o; }
    else              { int ti = j - 160; int o = ti / 5, m = ti - 5 * o; src = 160 + m * 16 + o; }
    buf[w][j] = c_old * nrow[j] + c_new_s * arow[src];
  }
  float ohv = (lane < 16) ? onehot[(size_t)node * 16 + lane] : 0.f;
  unsigned long long msk = __ballot(ohv > 0.5f);
  int kk = __ffsll((unsigned long long)msk) - 1;
  __syncthreads();
  #pragma unroll
  for (int rep = 0; rep < 4; ++rep) {
    int c = rep * 64 + lane;
    if (c >= 240) break;
    float d;
    if (c < 64) {
      const float* tp = T0 + (size_t)kk * 64 + c;
      float a = 0.f;
      for (int i = 0; i < 64; ++i) a = fmaf(buf[w][i], tp[(size_t)i * 1024], a);
      d = a;
    } else if (c < 160) {
      int vi = c - 64; int o = vi / 3, m = vi - o * 3;
      const float* tp = T1 + (size_t)kk * 32 + o;
      float a = 0.f;
      for (int i = 0; i < 32; ++i) a = fmaf(buf[w][64 + i * 3 + m], tp[(size_t)i * 512], a);
      d = a;
    } else {
      int ti = c - 160; int o = ti / 5, m = ti - o * 5;
      const float* tp = T2 + (size_t)kk * 16 + o;
      float a = 0.f;
      for (int i = 0; i < 16; ++i) a = fmaf(buf[w][160 + i * 5 + m], tp[(size_t)i * 256], a);
      d = a;
    }
    out[(size_t)node * 240 + c] = buf[w][c] + d;
  }
}

extern "C" void kernel_launch(void* const* d_in, const int* in_sizes, int n_in,
                              void* d_out, int out_size, void* d_ws, size_t ws_size,
                              hipStream_t stream) {
  (void)in_sizes; (void)n_in; (void)out_size; (void)ws_size;
  const float* latents       = (const float*)d_in[0];
  const float* node_features = (const float*)d_in[1];
  const float* edge_features = (const float*)d_in[2];
  const float* node_onehot   = (const float*)d_in[3];
  const float* ln_gn = (const float*)d_in[5];
  const float* ln_bn = (const float*)d_in[6];
  const float* ln_ge = (const float*)d_in[7];
  const float* ln_be = (const float*)d_in[8];
  const float* Wg    = (const float*)d_in[9];
  const float* W0    = (const float*)d_in[10];
  const float* W1    = (const float*)d_in[11];
  const float* W2    = (const float*)d_in[12];
  const float* P0    = (const float*)d_in[13];
  const float* b0    = (const float*)d_in[14];
  const float* P1    = (const float*)d_in[15];
  const float* P2    = (const float*)d_in[16];
  const float* Wenv  = (const float*)d_in[17];
  const float* benv  = (const float*)d_in[18];
  const float* T0    = (const float*)d_in[19];
  const float* T1    = (const float*)d_in[20];
  const float* T2    = (const float*)d_in[21];
  const int*   eidx  = (const int*)d_in[22];
  float* out = (float*)d_out;

  __bf16* nfn    = (__bf16*)d_ws;                         // [10000,240] bf16 reordered
  float*  agg    = (float*)((char*)d_ws + 4800000);       // [10000,240] f32 reordered
  __bf16* Wsw    = (__bf16*)((char*)d_ws + 14400000);     // swizzled weights (~503KB)
  float4* stats  = (float4*)((char*)d_ws + 15000000);     // [160000] edge-LN stats
  float*  gatesG = (float*)((char*)d_ws + 17600000);      // [160000,8] gates

  hipMemsetAsync(agg, 0, 2400000 * sizeof(float), stream);
  k_prep<<<(WTOT + 255) / 256, 256, 0, stream>>>(W0, W1, W2, Wenv, P0, P1, P2, Wsw);
  k_node_ln<<<N_NODES / 4, 256, 0, stream>>>(node_features, ln_gn, ln_bn, nfn);
  k_stats<<<N_EDGES / 4, 256, 0, stream>>>(edge_features, stats);
  k_gate<<<N_EDGES / 16, 256, 0, stream>>>(latents, Wg, gatesG);
  k_edge<<<N_EDGES / 32, 512, 0, stream>>>(latents, edge_features, nfn, eidx,
      ln_ge, ln_be, stats, gatesG, Wsw, b0, benv, agg);
  k_node<<<N_NODES / 4, 256, 0, stream>>>(node_features, agg, node_onehot, T0, T1, T2, out);
}

// Round 6
// 536.822 us; speedup vs baseline: 2.3825x; 2.3825x over previous
//
#include <hip/hip_runtime.h>
#include <math.h>

#define N_NODES 10000
#define N_EDGES 160000
#define EPS 1e-8f

typedef __attribute__((ext_vector_type(8))) __bf16 bf16x8;
typedef __attribute__((ext_vector_type(4))) float f32x4;

__device__ __forceinline__ f32x4 MFMA(bf16x8 a, bf16x8 b, f32x4 c){
  return __builtin_amdgcn_mfma_f32_16x16x32_bf16(a, b, c, 0, 0, 0);
}

__device__ __forceinline__ float wave_sum64(float x) {
  #pragma unroll
  for (int m = 32; m >= 1; m >>= 1) x += __shfl_xor(x, m, 64);
  return x;
}
__device__ __forceinline__ float gsum16(float x) {
  x += __shfl_xor(x, 1, 64); x += __shfl_xor(x, 2, 64);
  x += __shfl_xor(x, 4, 64); x += __shfl_xor(x, 8, 64);
  return x;
}

// ---- LDS (bf16 element offsets), 32-edge tile, XOR-swizzled X tiles ----
// X0: [0, 6144)       32 rows x 192   byte ^= (row&7)<<4
// X1: [6144, 15360)   96 rows x 96    (row = m*32+eg)
// X2: [15360, 25600)  160 rows x 64   (c16|e16|n16|zero16)
// aliases (unswizzled, own lifetime):
// O0: [0, 3840)       32 x 120
// O1: [6144, 9984)    96 x 40
// O2: [15360, 21760)  160 x 40
// Wv: [21760, 25600)  32 x 120   (dead X2 tail; written after bar3)
#define X0O 0
#define X1O 6144
#define X2O 15360
#define O0O 0
#define O1O 6144
#define O2O 15360
#define WvO 21760
#define SMEM_BYTES 52352   // 51200 bf16 + 1024 gates + 128 ecs

// swizzled-weight offsets (bf16 elements) -- validated layout
#define W0O 0
#define W1O 196608
#define W2O 221184
#define WEO 229376
#define P0O 245760
#define P1O 249856
#define P2O 250880
#define WTOT 251392

// ---------------- weight pre-swizzle ----------------
__device__ __forceinline__ void prep_seg(int u, const float* __restrict__ src,
                                         __bf16* __restrict__ dst,
                                         int NT, int KS, int Ka, int Na) {
  int per = NT * KS * 512;
  int e = u / per; int r = u - e * per;
  int nt = r / (KS * 512); r -= nt * KS * 512;
  int ks = r >> 9; int li = r & 511;
  int lane = li >> 3, j = li & 7;
  int k = ks * 32 + ((lane >> 4) << 3) + j;
  int n = nt * 16 + (lane & 15);
  float v = (k < Ka && n < Na) ? src[((size_t)e * Ka + k) * Na + n] : 0.f;
  dst[u] = (__bf16)v;
}

__global__ __launch_bounds__(256)
void k_prep(const float* __restrict__ W0, const float* __restrict__ W1,
            const float* __restrict__ W2, const float* __restrict__ We,
            const float* __restrict__ P0, const float* __restrict__ P1,
            const float* __restrict__ P2, __bf16* __restrict__ dst) {
  int t = blockIdx.x * 256 + threadIdx.x;
  if (t >= WTOT) return;
  if      (t < W1O) prep_seg(t - W0O, W0, dst + W0O, 8, 6, 192, 112);
  else if (t < W2O) prep_seg(t - W1O, W1, dst + W1O, 2, 3,  96,  32);
  else if (t < WEO) prep_seg(t - W2O, W2, dst + W2O, 1, 2,  48,  16);
  else if (t < P0O) prep_seg(t - WEO, We, dst + WEO, 8, 4, 128, 112);
  else if (t < P1O) prep_seg(t - P0O, P0, dst + P0O, 4, 2,  64,  64);
  else if (t < P2O) prep_seg(t - P1O, P1, dst + P1O, 2, 1,  32,  32);
  else              prep_seg(t - P2O, P2, dst + P2O, 1, 1,  16,  16);
}

// ---------------- node separable LN -> bf16, fragment-reordered ----------------
__global__ __launch_bounds__(256)
void k_node_ln(const float* __restrict__ nf, const float* __restrict__ gn,
               const float* __restrict__ bn, __bf16* __restrict__ nfn) {
  int node = blockIdx.x * 4 + (threadIdx.x >> 6);
  int lane = threadIdx.x & 63;
  const float* row = nf + (size_t)node * 240;
  __bf16* out = nfn + (size_t)node * 240;
  float s = row[lane];
  float mean = wave_sum64(s) * (1.f / 64.f);
  float d = s - mean;
  float var = wave_sum64(d * d) * (1.f / 64.f);
  float rstd = rsqrtf(var + EPS);
  out[lane] = (__bf16)(d * rstd * gn[lane] + bn[lane]);
  float v0 = row[64 + lane];
  float v1 = (lane < 32) ? row[128 + lane] : 0.f;
  float rsv = rsqrtf(wave_sum64(v0 * v0 + v1 * v1) * (1.f / 96.f) + EPS);
  { int vi = lane; int i = vi / 3, m = vi - 3 * i;
    out[64 + m * 32 + i] = (__bf16)(v0 * rsv * gn[64 + i]); }
  if (lane < 32) { int vi = 64 + lane; int i = vi / 3, m = vi - 3 * i;
    out[64 + m * 32 + i] = (__bf16)(v1 * rsv * gn[64 + i]); }
  float t0 = row[160 + lane];
  float t1 = (lane < 16) ? row[224 + lane] : 0.f;
  float rst = rsqrtf(wave_sum64(t0 * t0 + t1 * t1) * (1.f / 80.f) + EPS);
  { int ti = lane; int i = ti / 5, m = ti - 5 * i;
    out[160 + m * 16 + i] = (__bf16)(t0 * rst * gn[96 + i]); }
  if (lane < 16) { int ti = 64 + lane; int i = ti / 5, m = ti - 5 * i;
    out[160 + m * 16 + i] = (__bf16)(t1 * rst * gn[96 + i]); }
}

// ---------------- edge LN stats ----------------
__global__ __launch_bounds__(256)
void k_stats(const float* __restrict__ ef, float4* __restrict__ stats) {
  int row = blockIdx.x * 4 + (threadIdx.x >> 6);
  int lane = threadIdx.x & 63;
  const float* r = ef + (size_t)row * 240;
  float s = r[lane];
  float mean = wave_sum64(s) * (1.f / 64.f);
  float d = s - mean;
  float var = wave_sum64(d * d) * (1.f / 64.f);
  float rstd = rsqrtf(var + EPS);
  float v0 = r[64 + lane];
  float v1 = (lane < 32) ? r[128 + lane] : 0.f;
  float rsv = rsqrtf(wave_sum64(v0 * v0 + v1 * v1) * (1.f / 96.f) + EPS);
  float t0 = r[160 + lane];
  float t1 = (lane < 16) ? r[224 + lane] : 0.f;
  float rst = rsqrtf(wave_sum64(t0 * t0 + t1 * t1) * (1.f / 80.f) + EPS);
  if (lane == 0) stats[row] = make_float4(mean, rstd, rsv, rst);
}

// ---------------- gates: softmax(latents @ Wg) ----------------
__global__ __launch_bounds__(256)
void k_gate(const float* __restrict__ latents, const float* __restrict__ Wg,
            float* __restrict__ gatesG) {
  int row = blockIdx.x * 16 + (threadIdx.x >> 4);
  int sl = threadIdx.x & 15;
  const float* lrow = latents + (size_t)row * 128 + sl * 8;
  float4 u4 = *(const float4*)lrow;
  float4 w4 = *(const float4*)(lrow + 4);
  float lv[8] = {u4.x, u4.y, u4.z, u4.w, w4.x, w4.y, w4.z, w4.w};
  float ga[8] = {};
  #pragma unroll
  for (int dd = 0; dd < 8; ++dd) {
    const float* wgr = Wg + (sl * 8 + dd) * 8;
    #pragma unroll
    for (int k = 0; k < 8; ++k) ga[k] += lv[dd] * wgr[k];
  }
  #pragma unroll
  for (int k = 0; k < 8; ++k) ga[k] = gsum16(ga[k]);
  float mx = ga[0];
  #pragma unroll
  for (int k = 1; k < 8; ++k) mx = fmaxf(mx, ga[k]);
  float den = 0.f;
  #pragma unroll
  for (int k = 0; k < 8; ++k) { ga[k] = expf(ga[k] - mx); den += ga[k]; }
  float val = 0.f;
  #pragma unroll
  for (int k = 0; k < 8; ++k) if (sl == k) val = ga[k];
  if (sl < 8) gatesG[(size_t)row * 8 + sl] = val / den;
}

// ---------------- fused edge kernel (MFMA), 32 edges/block ----------------
// NOTE: launch_bounds (512,4): VGPR cap 128 (compiles to ~64); 3 blocks/CU
// then come from the 52.7KB LDS footprint (3x52.7 = 158KB <= 160KB).
// (512,6) in round 5 forced VGPR=40 -> catastrophic scratch spill.
__global__ __launch_bounds__(512, 4)
void k_edge(const float* __restrict__ latents, const float* __restrict__ ef,
            const __bf16* __restrict__ nfn, const int* __restrict__ eidx,
            const float* __restrict__ ln_ge, const float* __restrict__ ln_be,
            const float4* __restrict__ stats, const float* __restrict__ gatesG,
            const __bf16* __restrict__ Wsw,
            const float* __restrict__ pb0, const float* __restrict__ benv,
            float* __restrict__ agg) {
  __shared__ __align__(16) char smem[SMEM_BYTES];
  float* gatesL = (float*)(smem + 51200);
  int* ecsL = (int*)(smem + 52224);
  __bf16* SBF = (__bf16*)smem;

  const int tid = threadIdx.x;
  const int e0 = blockIdx.x * 32;
  const int w = tid >> 6, lane = tid & 63, kg = lane >> 4, l16 = lane & 15;
  const int eg = tid >> 4, sl = tid & 15;
  const int xsw = (eg & 7) << 4;          // staging-side swizzle (row&7 == eg&7)
  const int xswr = (l16 & 7) << 4;        // MFMA-A-read swizzle (row&7 == l16&7)

  // ---- hoisted loads ----
  const int ec = eidx[e0 + eg], en = eidx[N_EDGES + e0 + eg];
  if (tid < 32) ecsL[tid] = eidx[e0 + tid];
  if (tid < 256) gatesL[tid] = gatesG[(size_t)e0 * 8 + tid];
  uint2 cvr[4], nvr[4]; float4 evf[4];
  #pragma unroll
  for (int j = 0; j < 4; ++j) {
    int ch = j * 16 + sl;
    if (ch < 60) {
      int p = ch * 4;
      cvr[j] = *(const uint2*)(nfn + (size_t)ec * 240 + p);
      nvr[j] = *(const uint2*)(nfn + (size_t)en * 240 + p);
      evf[j] = *(const float4*)(ef + (size_t)(e0 + eg) * 240 + p);
    }
  }
  float4 st = stats[e0 + eg];   // mean, rstd, rsv, rst

  // ================= staging (pure copies + affine; no shuffles) =================
  {
    #pragma unroll
    for (int j = 0; j < 4; ++j) {
      int ch = j * 16 + sl;
      if (ch < 60) {
        int p = ch * 4;
        float e4[4] = {evf[j].x, evf[j].y, evf[j].z, evf[j].w};
        if (p < 64) {
          int off = X0O + eg * 192;
          *(uint2*)(smem + (((off + p) * 2) ^ xsw)) = cvr[j];
          *(uint2*)(smem + (((off + 128 + p) * 2) ^ xsw)) = nvr[j];
          __bf16 eb[4];
          #pragma unroll
          for (int t = 0; t < 4; ++t) {
            int c = p + t;
            eb[t] = (__bf16)((e4[t] - st.x) * st.y * ln_ge[c] + ln_be[c]);
          }
          *(uint2*)(smem + (((off + 64 + p) * 2) ^ xsw)) = *(uint2*)eb;
        } else if (p < 160) {
          int q = p - 64;
          int m = q >> 5, i = q & 31;
          int off = X1O + (m * 32 + eg) * 96;
          *(uint2*)(smem + (((off + i) * 2) ^ xsw)) = cvr[j];
          *(uint2*)(smem + (((off + 64 + i) * 2) ^ xsw)) = nvr[j];
          #pragma unroll
          for (int t = 0; t < 4; ++t) {
            int k = q + t; int ei = k / 3, em = k - 3 * ei;
            float y = e4[t] * st.z * ln_ge[64 + ei];
            *(__bf16*)(smem + (((X1O + (em * 32 + eg) * 96 + 32 + ei) * 2) ^ xsw)) = (__bf16)y;
          }
        } else {
          int q = p - 160;
          int m = q >> 4, i = q & 15;
          int off = X2O + (m * 32 + eg) * 64;
          *(uint2*)(smem + (((off + i) * 2) ^ xsw)) = cvr[j];
          *(uint2*)(smem + (((off + 32 + i) * 2) ^ xsw)) = nvr[j];
          #pragma unroll
          for (int t = 0; t < 4; ++t) {
            int k = q + t; int ei = k / 5, em = k - 5 * ei;
            float y = e4[t] * st.w * ln_ge[96 + ei];
            *(__bf16*)(smem + (((X2O + (em * 32 + eg) * 64 + 16 + ei) * 2) ^ xsw)) = (__bf16)y;
          }
        }
      }
    }
    // X2 K-pad zeros (cols 48..63), swizzled
    for (int z = tid; z < 640; z += 512) {
      int r = z >> 2, c4 = (z & 3) * 4;
      uint2 zz; zz.x = 0; zz.y = 0;
      *(uint2*)(smem + (((X2O + r * 64 + 48 + c4) * 2) ^ ((r & 7) << 4))) = zz;
    }
  }
  __syncthreads();   // bar0: X0/X1/X2/gates/ecs ready

  // ================= l0 MoE + fused silu/sigmoid epilogue =================
  {
    const int mt = w & 1, ntA = (w >> 1) * 2;
    f32x4 acc[2] = {};
    const __bf16* WB = Wsw + W0O;
    for (int ex = 0; ex < 8; ++ex) {
      f32x4 D[2] = {};
      #pragma unroll
      for (int ks = 0; ks < 6; ++ks) {
        bf16x8 a = *(const bf16x8*)(smem + (((X0O + (mt * 16 + l16) * 192 + ks * 32 + kg * 8) * 2) ^ xswr));
        bf16x8 bA = *(const bf16x8*)(WB + (((ex * 8 + ntA) * 6 + ks) << 9) + lane * 8);
        bf16x8 bB = *(const bf16x8*)(WB + (((ex * 8 + ntA + 1) * 6 + ks) << 9) + lane * 8);
        D[0] = MFMA(a, bA, D[0]); D[1] = MFMA(a, bB, D[1]);
      }
      #pragma unroll
      for (int jj = 0; jj < 4; ++jj) {
        float g = gatesL[(mt * 16 + kg * 4 + jj) * 8 + ex];
        acc[0][jj] += g * D[0][jj]; acc[1][jj] += g * D[1][jj];
      }
    }
    __syncthreads();   // bar1: all waves done reading X0
    #pragma unroll
    for (int ni = 0; ni < 2; ++ni) {
      int cc = (ntA + ni) * 16 + l16;
      if (cc < 112)
        #pragma unroll
        for (int jj = 0; jj < 4; ++jj) {
          float x = acc[ni][jj];
          float sg = 1.f / (1.f + expf(-x));
          float val = (cc < 64) ? x * sg : sg;
          SBF[O0O + (mt * 16 + kg * 4 + jj) * 120 + cc] = (__bf16)val;
        }
    }
  }

  // ================= l1 MoE + gated epilogue =================
  const int nu1 = (w < 4) ? 2 : 1;
  const int mtv0 = w >> 1, ntv = w & 1, mtv1 = (w >> 1) + 4;
  {
    f32x4 acc[2] = {};
    const __bf16* WB = Wsw + W1O;
    for (int ex = 0; ex < 8; ++ex) {
      f32x4 D[2] = {};
      #pragma unroll
      for (int ks = 0; ks < 3; ++ks) {
        bf16x8 b = *(const bf16x8*)(WB + (((ex * 2 + ntv) * 3 + ks) << 9) + lane * 8);
        bf16x8 a0 = *(const bf16x8*)(smem + (((X1O + (mtv0 * 16 + l16) * 96 + ks * 32 + kg * 8) * 2) ^ xswr));
        D[0] = MFMA(a0, b, D[0]);
        if (nu1 == 2) {
          bf16x8 a1 = *(const bf16x8*)(smem + (((X1O + (mtv1 * 16 + l16) * 96 + ks * 32 + kg * 8) * 2) ^ xswr));
          D[1] = MFMA(a1, b, D[1]);
        }
      }
      #pragma unroll
      for (int jj = 0; jj < 4; ++jj) {
        int r0 = mtv0 * 16 + kg * 4 + jj;
        acc[0][jj] += gatesL[(r0 & 31) * 8 + ex] * D[0][jj];
        if (nu1 == 2) {
          int r1 = mtv1 * 16 + kg * 4 + jj;
          acc[1][jj] += gatesL[(r1 & 31) * 8 + ex] * D[1][jj];
        }
      }
    }
    __syncthreads();   // bar2: X1 reads done; O0 visible
    const int o = ntv * 16 + l16;
    #pragma unroll
    for (int jj = 0; jj < 4; ++jj) {
      int r0 = mtv0 * 16 + kg * 4 + jj;
      float g0 = (float)SBF[O0O + (r0 & 31) * 120 + 64 + o];
      SBF[O1O + r0 * 40 + o] = (__bf16)(acc[0][jj] * g0);
      if (nu1 == 2) {
        int r1 = mtv1 * 16 + kg * 4 + jj;
        float g1 = (float)SBF[O0O + (r1 & 31) * 120 + 64 + o];
        SBF[O1O + r1 * 40 + o] = (__bf16)(acc[1][jj] * g1);
      }
    }
  }

  // ================= l2 MoE + gated epilogue =================
  const int nu2 = (w < 2) ? 2 : 1;
  const int mt20 = w, mt21 = w + 8;
  {
    f32x4 acc[2] = {};
    const __bf16* WB = Wsw + W2O;
    for (int ex = 0; ex < 8; ++ex) {
      f32x4 D[2] = {};
      #pragma unroll
      for (int ks = 0; ks < 2; ++ks) {
        bf16x8 b = *(const bf16x8*)(WB + ((ex * 2 + ks) << 9) + lane * 8);
        bf16x8 a0 = *(const bf16x8*)(smem + (((X2O + (mt20 * 16 + l16) * 64 + ks * 32 + kg * 8) * 2) ^ xswr));
        D[0] = MFMA(a0, b, D[0]);
        if (nu2 == 2) {
          bf16x8 a1 = *(const bf16x8*)(smem + (((X2O + (mt21 * 16 + l16) * 64 + ks * 32 + kg * 8) * 2) ^ xswr));
          D[1] = MFMA(a1, b, D[1]);
        }
      }
      #pragma unroll
      for (int jj = 0; jj < 4; ++jj) {
        int r0 = mt20 * 16 + kg * 4 + jj;
        acc[0][jj] += gatesL[(r0 & 31) * 8 + ex] * D[0][jj];
        if (nu2 == 2) {
          int r1 = mt21 * 16 + kg * 4 + jj;
          acc[1][jj] += gatesL[(r1 & 31) * 8 + ex] * D[1][jj];
        }
      }
    }
    __syncthreads();   // bar3: X2 reads done
    #pragma unroll
    for (int jj = 0; jj < 4; ++jj) {
      int r0 = mt20 * 16 + kg * 4 + jj;
      float g0 = (float)SBF[O0O + (r0 & 31) * 120 + 96 + l16];
      SBF[O2O + r0 * 40 + l16] = (__bf16)(acc[0][jj] * g0);
      SBF[O2O + r0 * 40 + 16 + l16] = (__bf16)0.f;
      if (nu2 == 2) {
        int r1 = mt21 * 16 + kg * 4 + jj;
        float g1 = (float)SBF[O0O + (r1 & 31) * 120 + 96 + l16];
        SBF[O2O + r1 * 40 + l16] = (__bf16)(acc[1][jj] * g1);
        SBF[O2O + r1 * 40 + 16 + l16] = (__bf16)0.f;
      }
    }
  }

  // ================= env weights (latents @ Wenv + benv) -> Wv (X2 tail) =====
  {
    const int mt = w >> 2, np = (w & 3) * 2;
    f32x4 acc[2] = {};
    const __bf16* WB = Wsw + WEO;
    #pragma unroll
    for (int ks = 0; ks < 4; ++ks) {
      bf16x8 a;
      const float* lp = latents + (size_t)(e0 + mt * 16 + l16) * 128 + ks * 32 + kg * 8;
      float4 u4 = *(const float4*)lp; float4 v4 = *(const float4*)(lp + 4);
      a[0]=(__bf16)u4.x; a[1]=(__bf16)u4.y; a[2]=(__bf16)u4.z; a[3]=(__bf16)u4.w;
      a[4]=(__bf16)v4.x; a[5]=(__bf16)v4.y; a[6]=(__bf16)v4.z; a[7]=(__bf16)v4.w;
      bf16x8 bA = *(const bf16x8*)(WB + ((np * 4 + ks) << 9) + lane * 8);
      bf16x8 bB = *(const bf16x8*)(WB + (((np + 1) * 4 + ks) << 9) + lane * 8);
      acc[0] = MFMA(a, bA, acc[0]); acc[1] = MFMA(a, bB, acc[1]);
    }
    #pragma unroll
    for (int ni = 0; ni < 2; ++ni) {
      int cc = (np + ni) * 16 + l16;
      if (cc < 112) {
        float bv = benv[cc];
        #pragma unroll
        for (int jj = 0; jj < 4; ++jj)
          SBF[WvO + (mt * 16 + kg * 4 + jj) * 120 + cc] = (__bf16)(acc[ni][jj] + bv);
      }
    }
  }
  __syncthreads();   // bar4: O0/O1/O2/Wv all visible

  // ================= lin_post s-path + coalesced scatter =================
  {
    const int mt = w & 1, nt = w >> 1;
    f32x4 ps = {};
    const __bf16* WB = Wsw + P0O;
    #pragma unroll
    for (int ks = 0; ks < 2; ++ks) {
      bf16x8 a = *(const bf16x8*)(SBF + O0O + (mt * 16 + l16) * 120 + ks * 32 + kg * 8);
      bf16x8 b = *(const bf16x8*)(WB + ((nt * 2 + ks) << 9) + lane * 8);
      ps = MFMA(a, b, ps);
    }
    int cc = nt * 16 + l16;
    float bias = pb0[cc];
    #pragma unroll
    for (int jj = 0; jj < 4; ++jj) {
      int row = mt * 16 + kg * 4 + jj;
      float msg = (ps[jj] + bias) * (float)SBF[WvO + row * 120 + cc];
      atomicAdd(&agg[(size_t)ecsL[row] * 240 + cc], msg);
    }
  }
  // ================= lin_post v-path + coalesced scatter =================
  {
    f32x4 pv[2] = {};
    const __bf16* WB = Wsw + P1O;
    bf16x8 b = *(const bf16x8*)(WB + (ntv << 9) + lane * 8);
    bf16x8 a0 = *(const bf16x8*)(SBF + O1O + (mtv0 * 16 + l16) * 40 + kg * 8);
    pv[0] = MFMA(a0, b, pv[0]);
    if (nu1 == 2) {
      bf16x8 a1 = *(const bf16x8*)(SBF + O1O + (mtv1 * 16 + l16) * 40 + kg * 8);
      pv[1] = MFMA(a1, b, pv[1]);
    }
    const int o = ntv * 16 + l16;
    #pragma unroll
    for (int jj = 0; jj < 4; ++jj) {
      int r0 = mtv0 * 16 + kg * 4 + jj;
      int m = r0 >> 5, eL = r0 & 31;
      float msg = pv[0][jj] * (float)SBF[WvO + eL * 120 + 64 + o];
      atomicAdd(&agg[(size_t)ecsL[eL] * 240 + 64 + m * 32 + o], msg);
      if (nu1 == 2) {
        int r1 = mtv1 * 16 + kg * 4 + jj;
        int m1 = r1 >> 5, eL1 = r1 & 31;
        float msg1 = pv[1][jj] * (float)SBF[WvO + eL1 * 120 + 64 + o];
        atomicAdd(&agg[(size_t)ecsL[eL1] * 240 + 64 + m1 * 32 + o], msg1);
      }
    }
  }
  // ================= lin_post t-path + coalesced scatter =================
  {
    f32x4 pt[2] = {};
    const __bf16* WB = Wsw + P2O;
    bf16x8 b = *(const bf16x8*)(WB + lane * 8);
    bf16x8 a0 = *(const bf16x8*)(SBF + O2O + (mt20 * 16 + l16) * 40 + kg * 8);
    pt[0] = MFMA(a0, b, pt[0]);
    if (nu2 == 2) {
      bf16x8 a1 = *(const bf16x8*)(SBF + O2O + (mt21 * 16 + l16) * 40 + kg * 8);
      pt[1] = MFMA(a1, b, pt[1]);
    }
    const int o = l16;
    #pragma unroll
    for (int jj = 0; jj < 4; ++jj) {
      int r0 = mt20 * 16 + kg * 4 + jj;
      int m = r0 >> 5, eL = r0 & 31;
      float msg = pt[0][jj] * (float)SBF[WvO + eL * 120 + 96 + o];
      atomicAdd(&agg[(size_t)ecsL[eL] * 240 + 160 + m * 16 + o], msg);
      if (nu2 == 2) {
        int r1 = mt21 * 16 + kg * 4 + jj;
        int m1 = r1 >> 5, eL1 = r1 & 31;
        float msg1 = pt[1][jj] * (float)SBF[WvO + eL1 * 120 + 96 + o];
        atomicAdd(&agg[(size_t)ecsL[eL1] * 240 + 160 + m1 * 16 + o], msg1);
      }
    }
  }
}

// ---------------- node residual + species TP (agg in reordered layout) ----------------
__global__ __launch_bounds__(256)
void k_node(const float* __restrict__ nf, const float* __restrict__ agg,
            const float* __restrict__ onehot, const float* __restrict__ T0,
            const float* __restrict__ T1, const float* __restrict__ T2,
            float* __restrict__ out) {
  int w = threadIdx.x >> 6;
  int lane = threadIdx.x & 63;
  int node = blockIdx.x * 4 + w;
  __shared__ float buf[4][240];
  const float* nrow = nf + (size_t)node * 240;
  const float* arow = agg + (size_t)node * 240;
  const float c_old = 0.894427190999916f;
  const float c_new_s = 0.447213595499958f * 0.25f;
  for (int j = lane; j < 240; j += 64) {
    int src;
    if (j < 64) src = j;
    else if (j < 160) { int vi = j - 64; int o = vi / 3, m = vi - 3 * o; src = 64 + m * 32 + o; }
    else              { int ti = j - 160; int o = ti / 5, m = ti - 5 * o; src = 160 + m * 16 + o; }
    buf[w][j] = c_old * nrow[j] + c_new_s * arow[src];
  }
  float ohv = (lane < 16) ? onehot[(size_t)node * 16 + lane] : 0.f;
  unsigned long long msk = __ballot(ohv > 0.5f);
  int kk = __ffsll((unsigned long long)msk) - 1;
  __syncthreads();
  #pragma unroll
  for (int rep = 0; rep < 4; ++rep) {
    int c = rep * 64 + lane;
    if (c >= 240) break;
    float d;
    if (c < 64) {
      const float* tp = T0 + (size_t)kk * 64 + c;
      float a = 0.f;
      for (int i = 0; i < 64; ++i) a = fmaf(buf[w][i], tp[(size_t)i * 1024], a);
      d = a;
    } else if (c < 160) {
      int vi = c - 64; int o = vi / 3, m = vi - o * 3;
      const float* tp = T1 + (size_t)kk * 32 + o;
      float a = 0.f;
      for (int i = 0; i < 32; ++i) a = fmaf(buf[w][64 + i * 3 + m], tp[(size_t)i * 512], a);
      d = a;
    } else {
      int ti = c - 160; int o = ti / 5, m = ti - o * 5;
      const float* tp = T2 + (size_t)kk * 16 + o;
      float a = 0.f;
      for (int i = 0; i < 16; ++i) a = fmaf(buf[w][160 + i * 5 + m], tp[(size_t)i * 256], a);
      d = a;
    }
    out[(size_t)node * 240 + c] = buf[w][c] + d;
  }
}

extern "C" void kernel_launch(void* const* d_in, const int* in_sizes, int n_in,
                              void* d_out, int out_size, void* d_ws, size_t ws_size,
                              hipStream_t stream) {
  (void)in_sizes; (void)n_in; (void)out_size; (void)ws_size;
  const float* latents       = (const float*)d_in[0];
  const float* node_features = (const float*)d_in[1];
  const float* edge_features = (const float*)d_in[2];
  const float* node_onehot   = (const float*)d_in[3];
  const float* ln_gn = (const float*)d_in[5];
  const float* ln_bn = (const float*)d_in[6];
  const float* ln_ge = (const float*)d_in[7];
  const float* ln_be = (const float*)d_in[8];
  const float* Wg    = (const float*)d_in[9];
  const float* W0    = (const float*)d_in[10];
  const float* W1    = (const float*)d_in[11];
  const float* W2    = (const float*)d_in[12];
  const float* P0    = (const float*)d_in[13];
  const float* b0    = (const float*)d_in[14];
  const float* P1    = (const float*)d_in[15];
  const float* P2    = (const float*)d_in[16];
  const float* Wenv  = (const float*)d_in[17];
  const float* benv  = (const float*)d_in[18];
  const float* T0    = (const float*)d_in[19];
  const float* T1    = (const float*)d_in[20];
  const float* T2    = (const float*)d_in[21];
  const int*   eidx  = (const int*)d_in[22];
  float* out = (float*)d_out;

  __bf16* nfn    = (__bf16*)d_ws;                         // [10000,240] bf16 reordered
  float*  agg    = (float*)((char*)d_ws + 4800000);       // [10000,240] f32 reordered
  __bf16* Wsw    = (__bf16*)((char*)d_ws + 14400000);     // swizzled weights (~503KB)
  float4* stats  = (float4*)((char*)d_ws + 15000000);     // [160000] edge-LN stats
  float*  gatesG = (float*)((char*)d_ws + 17600000);      // [160000,8] gates

  hipMemsetAsync(agg, 0, 2400000 * sizeof(float), stream);
  k_prep<<<(WTOT + 255) / 256, 256, 0, stream>>>(W0, W1, W2, Wenv, P0, P1, P2, Wsw);
  k_node_ln<<<N_NODES / 4, 256, 0, stream>>>(node_features, ln_gn, ln_bn, nfn);
  k_stats<<<N_EDGES / 4, 256, 0, stream>>>(edge_features, stats);
  k_gate<<<N_EDGES / 16, 256, 0, stream>>>(latents, Wg, gatesG);
  k_edge<<<N_EDGES / 32, 512, 0, stream>>>(latents, edge_features, nfn, eidx,
      ln_ge, ln_be, stats, gatesG, Wsw, b0, benv, agg);
  k_node<<<N_NODES / 4, 256, 0, stream>>>(node_features, agg, node_onehot, T0, T1, T2, out);
}